// Round 1
// 344.735 us; speedup vs baseline: 1.2984x; 1.2984x over previous
//
#include <hip/hip_runtime.h>

#define N_IN_CH 256
#define N_OUT_CH 64
#define XPAD 264   // 256 + 8 ushort pad: row stride 528 B -> conflict-free b128
#define NBK 512    // max buckets: rows/256 -> 391 for 100000
#define B1_E 8192  // edges per bin_kernel block

typedef __attribute__((ext_vector_type(8))) short short8;
typedef __attribute__((ext_vector_type(4))) float f32x4;

__device__ inline ushort f2bf(float f) {
    unsigned u = __float_as_uint(f);
    return (ushort)((u + 0x7FFFu + ((u >> 16) & 1u)) >> 16);   // RTNE
}
__device__ inline float bf2f(ushort u) {
    return __uint_as_float(((unsigned)u) << 16);
}

// --- Kernel 1: W [64][256] fp32 -> bf16 ---
__global__ void wbf_kernel(const float* __restrict__ W, ushort* __restrict__ Wbf) {
    int i = blockIdx.x * blockDim.x + threadIdx.x;
    if (i < N_OUT_CH * N_IN_CH) Wbf[i] = f2bf(W[i]);
}

// --- Kernel 2: Xp = X @ W^T via bf16 MFMA; 64 rows/block, K=256 in one shot ---
__global__ __launch_bounds__(256) void mfma_gemm_kernel(const float* __restrict__ X,
        const ushort* __restrict__ Wbf, ushort* __restrict__ Xp, int nrows) {
    __shared__ ushort Xs[64 * XPAD];
    __shared__ ushort Ws[64 * XPAD];

    const int tid = threadIdx.x;
    const int row0 = blockIdx.x * 64;

    #pragma unroll
    for (int it = 0; it < 16; ++it) {
        int f = it * 256 + tid;
        int n = f >> 6, c4 = f & 63;
        ushort4 v = *(const ushort4*)&Wbf[n * N_IN_CH + c4 * 4];
        *(ushort4*)&Ws[n * XPAD + c4 * 4] = v;
    }
    #pragma unroll
    for (int it = 0; it < 16; ++it) {
        int f = it * 256 + tid;
        int r = f >> 6, c4 = f & 63;
        int gr = row0 + r;
        float4 x = make_float4(0.f, 0.f, 0.f, 0.f);
        if (gr < nrows) x = *(const float4*)&X[(size_t)gr * N_IN_CH + c4 * 4];
        ushort4 u;
        u.x = f2bf(x.x); u.y = f2bf(x.y); u.z = f2bf(x.z); u.w = f2bf(x.w);
        *(ushort4*)&Xs[r * XPAD + c4 * 4] = u;
    }
    __syncthreads();

    const int wave = tid >> 6, lane = tid & 63;
    const int ml = lane & 15, quad = lane >> 4;

    const ushort* abase = &Xs[(wave * 16 + ml) * XPAD + quad * 8];
    short8 a[8];
    #pragma unroll
    for (int kt = 0; kt < 8; ++kt) a[kt] = *(const short8*)&abase[kt * 32];

    const ushort* bbase = &Ws[ml * XPAD + quad * 8];

    #pragma unroll
    for (int nt = 0; nt < 4; ++nt) {
        f32x4 acc = {0.f, 0.f, 0.f, 0.f};
        #pragma unroll
        for (int kt = 0; kt < 8; ++kt) {
            short8 b = *(const short8*)&bbase[nt * 16 * XPAD + kt * 32];
            acc = __builtin_amdgcn_mfma_f32_16x16x32_bf16(a[kt], b, acc, 0, 0, 0);
        }
        #pragma unroll
        for (int reg = 0; reg < 4; ++reg) {
            int gr = row0 + wave * 16 + quad * 4 + reg;
            if (gr < nrows)
                Xp[(size_t)gr * N_OUT_CH + nt * 16 + ml] = f2bf(acc[reg]);
        }
    }
}

// --- Bucket histogram: 391 bins (row >> 8), LDS-staged ---
__global__ __launch_bounds__(256) void bhist_kernel(const int* __restrict__ rows,
        int* __restrict__ bcnt, int nnz, int nb) {
    __shared__ int h[NBK];
    for (int i = threadIdx.x; i < nb; i += 256) h[i] = 0;
    __syncthreads();
    for (int e = blockIdx.x * 256 + threadIdx.x; e < nnz; e += gridDim.x * 256)
        atomicAdd(&h[rows[e] >> 8], 1);
    __syncthreads();
    for (int i = threadIdx.x; i < nb; i += 256) {
        int c = h[i];
        if (c) atomicAdd(&bcnt[i], c);
    }
}

// --- Bucket exclusive scan (single block, <=512 buckets), init bcur too ---
__global__ __launch_bounds__(256) void bscan_kernel(const int* __restrict__ bcnt,
        int* __restrict__ bstart, int* __restrict__ bcur, int nb, int nnz) {
    __shared__ int sh[2 * NBK == 1024 ? 512 : 512];  // 512 ints
    int t = threadIdx.x;
    sh[t]       = (t < nb) ? bcnt[t] : 0;
    sh[t + 256] = (t + 256 < nb) ? bcnt[t + 256] : 0;
    __syncthreads();
    #pragma unroll
    for (int d = 1; d < 512; d <<= 1) {
        int a = (t >= d) ? sh[t - d] : 0;
        int c = sh[t + 256 - d];        // t+256 >= d always (d <= 256)
        __syncthreads();
        sh[t] += a;
        sh[t + 256] += c;
        __syncthreads();
    }
    int e0 = (t == 0) ? 0 : sh[t - 1];
    int e1 = sh[t + 255];
    if (t < nb)       { bstart[t] = e0;       bcur[t] = e0; }
    if (t + 256 < nb) { bstart[t + 256] = e1; bcur[t + 256] = e1; }
    if (t == 0) bstart[nb] = nnz;
}

// --- B1: bin-append. Per block: LDS count -> 1 atomic per bucket -> contiguous
//     per-(block,bucket) segment writes of (row_local<<17|col, val). ---
__global__ __launch_bounds__(256) void bin_kernel(const int* __restrict__ rows,
        const int* __restrict__ cols, const float* __restrict__ vals,
        int* __restrict__ bcur, int2* __restrict__ colbuf, int nnz, int nb) {
    __shared__ int cnt[NBK];
    __shared__ int base[NBK];
    const int t = threadIdx.x;
    const int e0 = blockIdx.x * B1_E;

    for (int i = t; i < nb; i += 256) cnt[i] = 0;
    __syncthreads();
    #pragma unroll
    for (int it = 0; it < B1_E / 256; ++it) {
        int e = e0 + it * 256 + t;
        if (e < nnz) atomicAdd(&cnt[rows[e] >> 8], 1);
    }
    __syncthreads();
    for (int i = t; i < nb; i += 256) {
        int c = cnt[i];
        base[i] = c ? atomicAdd(&bcur[i], c) : 0;
        cnt[i] = 0;
    }
    __syncthreads();
    #pragma unroll
    for (int it = 0; it < B1_E / 256; ++it) {
        int e = e0 + it * 256 + t;
        if (e < nnz) {
            int r = rows[e];
            int b = r >> 8;
            int pos = base[b] + atomicAdd(&cnt[b], 1);
            int2 cv;
            cv.x = cols[e] | ((r & 255) << 17);   // col < 2^17, row_local 8 bits
            cv.y = __float_as_int(vals[e]);
            colbuf[pos] = cv;
        }
    }
}

// --- B2: per-bucket finalize. One block per bucket: local 256-row histogram +
//     scan in LDS, write CSR starts[], scatter (col,val) within 32 KB window. ---
__global__ __launch_bounds__(256) void bucket_kernel(const int* __restrict__ bstart,
        const int2* __restrict__ colbuf, int* __restrict__ starts,
        int2* __restrict__ colval, int nrows) {
    __shared__ int rc[256];
    __shared__ int rb[256];
    const int b = blockIdx.x, t = threadIdx.x;
    const int bs = bstart[b], be = bstart[b + 1];

    rc[t] = 0;
    __syncthreads();
    for (int i = bs + t; i < be; i += 256)
        atomicAdd(&rc[(colbuf[i].x >> 17) & 255], 1);
    __syncthreads();
    // inclusive Hillis-Steele scan over 256
    #pragma unroll
    for (int d = 1; d < 256; d <<= 1) {
        int a = (t >= d) ? rc[t - d] : 0;
        __syncthreads();
        rc[t] += a;
        __syncthreads();
    }
    int excl = (t == 0) ? 0 : rc[t - 1];
    __syncthreads();            // all excl reads done before rc reused
    rb[t] = excl;
    rc[t] = 0;
    int row = (b << 8) + t;
    if (row < nrows) starts[row] = bs + excl;
    __syncthreads();
    for (int i = bs + t; i < be; i += 256) {
        int2 cv = colbuf[i];
        int rl = (cv.x >> 17) & 255;
        int pos = bs + rb[rl] + atomicAdd(&rc[rl], 1);
        int2 o;
        o.x = cv.x & 0x1FFFF;
        o.y = cv.y;
        colval[pos] = o;
    }
}

// --- Kernel 3: CSR SpMM, bf16 gathers, unroll-4 for MLP ---
__global__ __launch_bounds__(256) void spmm_csr_kernel(const int* __restrict__ starts,
        const int2* __restrict__ colval, const ushort* __restrict__ Xp,
        float* __restrict__ out, int nrows, int nnz) {
    int t = blockIdx.x * blockDim.x + threadIdx.x;
    int row = t >> 6;
    int lane = t & 63;
    if (row >= nrows) return;
    int start = starts[row];
    int end = (row + 1 < nrows) ? starts[row + 1] : nnz;
    float a0 = 0.f, a1 = 0.f, a2 = 0.f, a3 = 0.f;
    int i = start;
    for (; i + 4 <= end; i += 4) {
        int2 c0 = colval[i], c1 = colval[i + 1], c2 = colval[i + 2], c3 = colval[i + 3];
        float x0 = bf2f(Xp[(size_t)c0.x * N_OUT_CH + lane]);
        float x1 = bf2f(Xp[(size_t)c1.x * N_OUT_CH + lane]);
        float x2 = bf2f(Xp[(size_t)c2.x * N_OUT_CH + lane]);
        float x3 = bf2f(Xp[(size_t)c3.x * N_OUT_CH + lane]);
        a0 += __int_as_float(c0.y) * x0;
        a1 += __int_as_float(c1.y) * x1;
        a2 += __int_as_float(c2.y) * x2;
        a3 += __int_as_float(c3.y) * x3;
    }
    for (; i < end; ++i) {
        int2 cv = colval[i];
        a0 += __int_as_float(cv.y) * bf2f(Xp[(size_t)cv.x * N_OUT_CH + lane]);
    }
    out[(size_t)row * N_OUT_CH + lane] = (a0 + a1) + (a2 + a3);
}

// --- Fallback atomic SpMM (ws too small — not expected) ---
__global__ __launch_bounds__(256) void spmm_atomic_kernel(const int* __restrict__ rows,
        const int* __restrict__ cols, const float* __restrict__ vals,
        const ushort* __restrict__ Xp, float* __restrict__ out, int nnz) {
    int t = blockIdx.x * blockDim.x + threadIdx.x;
    int e = t >> 6;
    int c = t & 63;
    if (e < nnz) {
        atomicAdd(&out[(size_t)rows[e] * N_OUT_CH + c],
                  vals[e] * bf2f(Xp[(size_t)cols[e] * N_OUT_CH + c]));
    }
}

extern "C" void kernel_launch(void* const* d_in, const int* in_sizes, int n_in,
                              void* d_out, int out_size, void* d_ws, size_t ws_size,
                              hipStream_t stream) {
    const float* X      = (const float*)d_in[2];
    const float* W      = (const float*)d_in[3];
    const int*   L_rows = (const int*)d_in[4];
    const int*   L_cols = (const int*)d_in[5];
    const float* L_vals = (const float*)d_in[6];
    float* out = (float*)d_out;

    const int nrows = in_sizes[2] / N_IN_CH;   // 100000
    const int nnz   = in_sizes[4];             // 1600000
    const int nb    = (nrows + 255) >> 8;      // 391 buckets

    // workspace layout (8B-aligned)
    size_t off_wbf = 0;                                             // 32 KB
    size_t off_xp  = 65536;
    size_t xp_b    = (size_t)nrows * N_OUT_CH * 2;                  // Xp bf16: 12.8 MB
    size_t off_st  = off_xp + ((xp_b + 7) & ~(size_t)7);
    size_t off_bs  = off_st + (((size_t)nrows * 4 + 7) & ~(size_t)7);     // starts
    size_t off_bc  = off_bs + (((size_t)(nb + 1) * 4 + 7) & ~(size_t)7);  // bstart
    size_t off_bh  = off_bc + (((size_t)nb * 4 + 7) & ~(size_t)7);        // bcur
    size_t off_cv  = off_bh + (((size_t)nb * 4 + 7) & ~(size_t)7);        // bcnt
    size_t need    = off_cv + (size_t)nnz * 8;                      // colval: 12.8 MB

    ushort* Wbf = (ushort*)((char*)d_ws + off_wbf);
    ushort* Xp  = (ushort*)((char*)d_ws + off_xp);

    wbf_kernel<<<(N_OUT_CH * N_IN_CH + 255) / 256, 256, 0, stream>>>(W, Wbf);
    mfma_gemm_kernel<<<(nrows + 63) / 64, 256, 0, stream>>>(X, Wbf, Xp, nrows);

    if (ws_size >= need && nb <= NBK) {
        int*  starts = (int*)((char*)d_ws + off_st);
        int*  bstart = (int*)((char*)d_ws + off_bs);
        int*  bcur   = (int*)((char*)d_ws + off_bc);
        int*  bcnt   = (int*)((char*)d_ws + off_bh);
        int2* colval = (int2*)((char*)d_ws + off_cv);
        int2* colbuf = (int2*)d_out;   // 12.8 MB scratch inside the 25.6 MB output

        hipMemsetAsync(bcnt, 0, (size_t)nb * 4, stream);
        bhist_kernel<<<512, 256, 0, stream>>>(L_rows, bcnt, nnz, nb);
        bscan_kernel<<<1, 256, 0, stream>>>(bcnt, bstart, bcur, nb, nnz);
        bin_kernel<<<(nnz + B1_E - 1) / B1_E, 256, 0, stream>>>(L_rows, L_cols, L_vals,
                                                                bcur, colbuf, nnz, nb);
        bucket_kernel<<<nb, 256, 0, stream>>>(bstart, colbuf, starts, colval, nrows);

        long long total = (long long)nrows * 64;
        spmm_csr_kernel<<<(int)((total + 255) / 256), 256, 0, stream>>>(starts, colval,
                                                                        Xp, out, nrows, nnz);
    } else {
        hipMemsetAsync(d_out, 0, (size_t)out_size * sizeof(float), stream);
        long long total = (long long)nnz * 64;
        spmm_atomic_kernel<<<(int)((total + 255) / 256), 256, 0, stream>>>(
            L_rows, L_cols, L_vals, Xp, out, nnz);
    }
}